// Round 6
// baseline (880.561 us; speedup 1.0000x reference)
//
#include <hip/hip_runtime.h>
#include <hip/hip_bf16.h>

// Attention4DDownsample — fused, one workgroup per batch element.
// R10: "slim phases" restructure. Counter forensics across R5-R9: excess HBM
// write always equals the largest per-thread f32 array (R8/R9: va[64]+acc[16]
// = 320B/thr -> 330MB; R6: xv[28]=112B -> 228MB), i.e. accumulator ARRAYS
// >= ~16 dwords spill to scratch under the allocator's immovable 64-VGPR
// target; small live sets never spill. So: no phase may hold >16-dword arrays.
//  - v GEMM split into 4 passes x 128 ch, acc[4] (16 f32) each, retired to
//    vsm [128][72] overlaying dead kt/qsm after PD
//  - PD moved before the v-path (kt dies early)
//  - fused v_local+PV per pass (4+4 f32); cross-pass res[4][4] (16 f32)
//  - PA keeps R8's rolling 3x7 window (~35 live)
// 12 barriers, LDS 76,304 B (2 blocks/CU).

#define DIMC 384
#define NPOS 49
#define NHKD 128
#define DHC  512
#define OUTC 384

// ws bf16 weight offsets (elements)
#define OFF_KW  0
#define OFF_VW  49152
#define OFF_QPW 245760
#define OFF_PW  294912
#define W_TOT   491520
// BN fold table (float2, after W_TOT bf16 elems): k,q,v,vl,p
#define BN_K  0
#define BN_Q  128
#define BN_V  256
#define BN_VL 768
#define BN_P  1280
#define BN_TOT 1664
// abf table (f32, after BN table): [8][16*49] gathered bias
#define ABF_ELEMS (8 * 784)

// LDS (bf16 element offsets), total 38,152 elems = 76,304 B (2 blocks/CU)
#define XS_OFF   0        // xs [49][392]; rout [16][520] overlays after vGEMM pass 3
#define KT_OFF   19208    // kt [64][136]; vsm [128][72] (9216) overlays after PD
#define QSM_OFF  27912    // qsm [8][16][16] (2048); tail of vsm's 10752 window
#define QIN_OFF  29960    // qin [16][392]; attnS [8][16][64] (swz) overlays after qGEMM
#define SMEM_ELEMS 38152

typedef __attribute__((ext_vector_type(8))) __bf16 bf16x8;
typedef __attribute__((ext_vector_type(4))) float f32x4;

static __device__ __forceinline__ __hip_bfloat16 f2b(float x) { return __float2bfloat16(x); }
static __device__ __forceinline__ float b2f(__hip_bfloat16 x) { return __bfloat162float(x); }
static __device__ __forceinline__ bf16x8 ld8(const __hip_bfloat16* p) { return *(const bf16x8*)p; }
static __device__ __forceinline__ f32x4 fzero() {
  f32x4 z; z[0] = 0.f; z[1] = 0.f; z[2] = 0.f; z[3] = 0.f; return z;
}
static __device__ __forceinline__ bf16x8 bzero() {
  bf16x8 z;
  #pragma unroll
  for (int j = 0; j < 8; ++j) z[j] = (__bf16)0.0f;
  return z;
}

// ---------------- prep: weights->bf16, BN fold->float2, bias gather->abf ----------------
__global__ void prep_weights(const float* __restrict__ kw, const float* __restrict__ vw,
                             const float* __restrict__ qpw, const float* __restrict__ pw,
                             const float* __restrict__ kb,  const float* __restrict__ kbn,
                             const float* __restrict__ qpb, const float* __restrict__ qbn,
                             const float* __restrict__ vb,  const float* __restrict__ vbn,
                             const float* __restrict__ vlb, const float* __restrict__ vlbn,
                             const float* __restrict__ pb,  const float* __restrict__ pbn,
                             const float* __restrict__ ab,  const int* __restrict__ bidx,
                             int n_off,
                             __hip_bfloat16* __restrict__ wsb) {
  const int gid = blockIdx.x * blockDim.x + threadIdx.x;
  const int stride = gridDim.x * blockDim.x;
  for (int i = gid; i < W_TOT; i += stride) {
    float v;
    if (i < OFF_VW)       v = kw[i - OFF_KW];
    else if (i < OFF_QPW) v = vw[i - OFF_VW];
    else if (i < OFF_PW)  v = qpw[i - OFF_QPW];
    else                  v = pw[i - OFF_PW];
    wsb[i] = f2b(v);
  }
  float2* bnt = (float2*)(wsb + W_TOT);
  for (int i = gid; i < BN_TOT; i += stride) {
    const float *bn, *cb; int ch, C;
    if (i < BN_Q)        { bn = kbn;  cb = kb;  ch = i;         C = NHKD; }
    else if (i < BN_V)   { bn = qbn;  cb = qpb; ch = i - BN_Q;  C = NHKD; }
    else if (i < BN_VL)  { bn = vbn;  cb = vb;  ch = i - BN_V;  C = DHC;  }
    else if (i < BN_P)   { bn = vlbn; cb = vlb; ch = i - BN_VL; C = DHC;  }
    else                 { bn = pbn;  cb = pb;  ch = i - BN_P;  C = OUTC; }
    const float g = bn[ch], be = bn[C + ch], mu = bn[2*C + ch], va = bn[3*C + ch];
    const float s = g * rsqrtf(va + 1e-5f);
    bnt[i] = make_float2(s, be + (cb[ch] - mu) * s);
  }
  float* abf = (float*)((char*)bnt + BN_TOT * 8);
  for (int i = gid; i < ABF_ELEMS; i += stride) {
    const int h = i / 784, j = i - h * 784;
    abf[i] = ab[h * n_off + bidx[j]];
  }
}

// ---------------- main fused kernel ----------------
__global__ __launch_bounds__(512) void attn4d_kernel(
    const float* __restrict__ x,
    const float* __restrict__ qlw, const float* __restrict__ qlb,
    const float* __restrict__ vlw,
    const __hip_bfloat16* __restrict__ wsb,
    float* __restrict__ out)
{
  __shared__ __align__(16) __hip_bfloat16 smem[SMEM_ELEMS];
  __hip_bfloat16* xs    = smem + XS_OFF;     // [49][392]
  __hip_bfloat16* rout  = smem + XS_OFF;     // [16][520], overlays xs post pass-3 vGEMM
  __hip_bfloat16* kt    = smem + KT_OFF;     // [64][136]
  __hip_bfloat16* vsm   = smem + KT_OFF;     // [128][72], overlays kt(+qsm) post-PD
  __hip_bfloat16* qsm   = smem + QSM_OFF;    // [8][16][16]
  __hip_bfloat16* qin   = smem + QIN_OFF;    // [16][392]
  __hip_bfloat16* attnS = smem + QIN_OFF;    // [8][16][64] swz, overlays qin

  const __hip_bfloat16* kwb  = wsb + OFF_KW;
  const __hip_bfloat16* vwb  = wsb + OFF_VW;
  const __hip_bfloat16* qpwb = wsb + OFF_QPW;
  const __hip_bfloat16* pwb  = wsb + OFF_PW;
  const float2* bnt = (const float2*)(wsb + W_TOT);
  const float*  abf = (const float*)((const char*)bnt + BN_TOT * 8);

  const int tid  = threadIdx.x;
  const int lane = tid & 63;
  const int wave = tid >> 6;     // 0..7
  const int quad = lane >> 4;    // 0..3
  const int l15  = lane & 15;
  const int b    = blockIdx.x;

  // ---- P0: stage x[b] (fp32 global) -> xs[n][c] bf16 transposed, b128 LDS writes
  {
    const float* xg = x + (size_t)b * (DIMC * NPOS);
    for (int j = tid; j < NPOS * (DIMC / 8); j += 512) {   // 2352 jobs
      const int n  = j % 49;
      const int c0 = (j / 49) * 8;
      bf16x8 v;
      #pragma unroll
      for (int k = 0; k < 8; ++k)
        v[k] = (__bf16)(xg[(c0 + k) * 49 + n]);
      *(bf16x8*)&xs[n * 392 + c0] = v;
    }
  }
  __syncthreads();   // bar1

  // ---- PA: qin[nq][c] = dw3x3 s2 p1 + avgpool2. Rolling 3x7 window (~35 live).
  if (tid < 384) {
    const int c = tid;
    float wq[9];
    #pragma unroll
    for (int j = 0; j < 9; ++j) wq[j] = qlw[c * 9 + j];
    const float cb = qlb[c];
    #pragma unroll
    for (int oh = 0; oh < 4; ++oh) {
      float w[3][7];   // rows 2oh-1, 2oh, 2oh+1 (zeros when out of range)
      #pragma unroll
      for (int i = 0; i < 7; ++i) {
        w[0][i] = (oh > 0) ? b2f(xs[((2*oh - 1) * 7 + i) * 392 + c]) : 0.f;
        w[1][i] = b2f(xs[((2*oh) * 7 + i) * 392 + c]);
        w[2][i] = (oh < 3) ? b2f(xs[((2*oh + 1) * 7 + i) * 392 + c]) : 0.f;
      }
      #pragma unroll
      for (int ow = 0; ow < 4; ++ow) {
        float a = cb;
        #pragma unroll
        for (int kh = 0; kh < 3; ++kh) {
          #pragma unroll
          for (int kwi = 0; kwi < 3; ++kwi) {
            const int iw = 2 * ow - 1 + kwi;
            if (iw < 0 || iw > 6) continue;
            a += wq[kh * 3 + kwi] * w[kh][iw];
          }
        }
        if (oh < 3 && ow < 3)
          a += 0.25f * (w[1][2*ow] + w[1][2*ow + 1] + w[2][2*ow] + w[2][2*ow + 1]);
        qin[(oh * 4 + ow) * 392 + c] = f2b(a);
      }
    }
  }
  __syncthreads();   // bar2

  // ---- kGEMM: wave = M-tile, 4 N-tiles, per-nt guarded z (live ~25)
  {
    const int mt = wave;
    f32x4 acc[4];
    #pragma unroll
    for (int nt = 0; nt < 4; ++nt) acc[nt] = fzero();
    for (int ks = 0; ks < 12; ++ks) {
      const int c0 = ks * 32 + quad * 8;
      bf16x8 a = ld8(&kwb[(mt * 16 + l15) * DIMC + c0]);
      #pragma unroll
      for (int nt = 0; nt < 4; ++nt) {
        const int n = nt * 16 + l15;
        bf16x8 z = (n < 49) ? ld8(&xs[n * 392 + c0]) : bzero();
        acc[nt] = __builtin_amdgcn_mfma_f32_16x16x32_bf16(a, z, acc[nt], 0, 0, 0);
      }
    }
    #pragma unroll
    for (int r = 0; r < 4; ++r) {
      const int oc = mt * 16 + quad * 4 + r;
      const float2 so = bnt[BN_K + oc];
      #pragma unroll
      for (int nt = 0; nt < 4; ++nt) {
        const int n = nt * 16 + l15;
        if (n < 49) kt[n * 136 + oc] = f2b(acc[nt][r] * so.x + so.y);
        // rows 49..63 stale garbage: feed only masked nk>=49 logits (discarded)
      }
    }
  }

  // ---- qGEMM: wave = M-tile (head) -> qsm[h][nq][kd]
  {
    const int mt = wave;
    f32x4 acc = fzero();
    for (int ks = 0; ks < 12; ++ks) {
      const int c0 = ks * 32 + quad * 8;
      bf16x8 bv = ld8(&qin[l15 * 392 + c0]);
      bf16x8 av = ld8(&qpwb[(mt * 16 + l15) * DIMC + c0]);
      acc = __builtin_amdgcn_mfma_f32_16x16x32_bf16(av, bv, acc, 0, 0, 0);
    }
    #pragma unroll
    for (int r = 0; r < 4; ++r) {
      const int oc = mt * 16 + quad * 4 + r;
      const float2 so = bnt[BN_Q + oc];
      qsm[mt * 256 + l15 * 16 + (oc & 15)] = f2b(acc[r] * so.x + so.y);
    }
  }
  __syncthreads();   // bar3 — kt/qsm ready; qin dead

  // ---- PD: QK^T*scale + abf bias, softmax -> attnS (XOR-swizzled, over dead qin)
  {
    const int h = wave;
    bf16x8 av = (quad < 2) ? ld8(&qsm[h * 256 + l15 * 16 + quad * 8]) : bzero();
    float p[4][4];
    #pragma unroll
    for (int t = 0; t < 4; ++t) {
      bf16x8 bv = (quad < 2) ? ld8(&kt[(t * 16 + l15) * 136 + h * 16 + quad * 8]) : bzero();
      f32x4 lg = __builtin_amdgcn_mfma_f32_16x16x32_bf16(av, bv, fzero(), 0, 0, 0);
      #pragma unroll
      for (int r = 0; r < 4; ++r) {
        const int nq = quad * 4 + r;
        const int nk = t * 16 + l15;
        float val = -30000.f;
        if (nk < 49) val = lg[r] * 0.25f + abf[h * 784 + nq * 49 + nk];
        p[t][r] = val;
      }
    }
    #pragma unroll
    for (int r = 0; r < 4; ++r) {
      float m = fmaxf(fmaxf(p[0][r], p[1][r]), fmaxf(p[2][r], p[3][r]));
      m = fmaxf(m, __shfl_xor(m, 1));
      m = fmaxf(m, __shfl_xor(m, 2));
      m = fmaxf(m, __shfl_xor(m, 4));
      m = fmaxf(m, __shfl_xor(m, 8));
      float e[4], sum = 0.f;
      #pragma unroll
      for (int t = 0; t < 4; ++t) { e[t] = __expf(p[t][r] - m); sum += e[t]; }
      sum += __shfl_xor(sum, 1);
      sum += __shfl_xor(sum, 2);
      sum += __shfl_xor(sum, 4);
      sum += __shfl_xor(sum, 8);
      const float inv = 1.f / sum;
      #pragma unroll
      for (int t = 0; t < 4; ++t) p[t][r] = e[t] * inv;   // exactly 0 for nk>=49
    }
    #pragma unroll
    for (int r = 0; r < 4; ++r) {
      const int nq = quad * 4 + r;
      #pragma unroll
      for (int t = 0; t < 4; ++t) {
        const int nk = t * 16 + l15;
        attnS[h * 1024 + nq * 64 + (nk ^ ((nq & 7) << 3))] = f2b(p[t][r]);
      }
    }
  }
  __syncthreads();   // bar4 — attnS ready; kt/qsm dead (vsm may overlay)

  // ================= v-path: 4 passes x 128 ch, slim accumulators =================
  float res[4][4];   // per-lane relu(xa+vloc) for ch = p*128 + wave*16 + quad*4 + r
  #pragma unroll
  for (int p = 0; p < 4; ++p) {
    // -- vGEMM pass p: wave = (nt = w&3, mgrp = w>>2 -> 4 M-tiles); acc[4] only
    {
      const int nt   = wave & 3;
      const int mgrp = wave >> 2;
      const int n    = nt * 16 + l15;
      f32x4 acc[4];
      #pragma unroll
      for (int i = 0; i < 4; ++i) acc[i] = fzero();
      for (int ks = 0; ks < 12; ++ks) {
        const int c0 = ks * 32 + quad * 8;
        bf16x8 z = (n < 49) ? ld8(&xs[n * 392 + c0]) : bzero();
        #pragma unroll
        for (int i = 0; i < 4; ++i) {
          bf16x8 a = ld8(&vwb[(p * 128 + (mgrp * 4 + i) * 16 + l15) * DIMC + c0]);
          acc[i] = __builtin_amdgcn_mfma_f32_16x16x32_bf16(a, z, acc[i], 0, 0, 0);
        }
      }
      #pragma unroll
      for (int i = 0; i < 4; ++i)
        #pragma unroll
        for (int r = 0; r < 4; ++r) {
          const int chl = (mgrp * 4 + i) * 16 + quad * 4 + r;
          const float2 so = bnt[BN_V + p * 128 + chl];
          // all n incl. 49..63 pads (finite) — PV multiplies pads by attn==0
          vsm[chl * 72 + n] = f2b(acc[i][r] * so.x + so.y);
        }
    }
    __syncthreads();   // barA — vsm pass p ready; (p==3): xs dead

    // -- fused v_local + PV: wave owns 16 ch; lane: ch = quad*4+r, pos = l15
    {
      const int pos = l15, oh = pos >> 2, ow = pos & 3;
      float vloc[4];
      #pragma unroll
      for (int r = 0; r < 4; ++r) {
        const int chl = wave * 16 + quad * 4 + r;
        const int gch = p * 128 + chl;
        float a = 0.f;
        #pragma unroll
        for (int kh = 0; kh < 3; ++kh) {
          #pragma unroll
          for (int kwi = 0; kwi < 3; ++kwi) {
            const int ih = 2 * oh - 1 + kh;
            const int iw = 2 * ow - 1 + kwi;
            const bool ok = ((unsigned)ih <= 6u) && ((unsigned)iw <= 6u);
            const int e = ok ? (ih * 7 + iw) : 0;
            const float tap = b2f(vsm[chl * 72 + e]);
            a += ok ? vlw[gch * 9 + kh * 3 + kwi] * tap : 0.f;
          }
        }
        const float2 so = bnt[BN_VL + gch];
        vloc[r] = a * so.x + so.y;
      }
      const int h = p * 2 + (wave >> 2);
      f32x4 pacc = fzero();
      #pragma unroll
      for (int ks = 0; ks < 2; ++ks) {
        const int k0 = ks * 32 + quad * 8;
        bf16x8 avv = ld8(&vsm[(wave * 16 + l15) * 72 + k0]);                      // A[ch][nk]
        bf16x8 bvv = ld8(&attnS[h * 1024 + l15 * 64 + (k0 ^ ((l15 & 7) << 3))]);  // B[nq][nk]
        pacc = __builtin_amdgcn_mfma_f32_16x16x32_bf16(avv, bvv, pacc, 0, 0, 0);
      }
      #pragma unroll
      for (int r = 0; r < 4; ++r)
        res[p][r] = fmaxf(pacc[r] + vloc[r], 0.f);
    }

    // after pass 3's barA, xs is dead -> flush res to rout (overlays xs)
    if (p == 3) {
      #pragma unroll
      for (int pp = 0; pp < 4; ++pp)
        #pragma unroll
        for (int r = 0; r < 4; ++r) {
          const int gch = pp * 128 + wave * 16 + quad * 4 + r;
          rout[l15 * 520 + gch] = f2b(res[pp][r]);
        }
    }
    __syncthreads();   // barB — vsm reusable / (p==3) rout ready
  }

  // ---- PF: proj GEMM — 24 M-tiles over 8 waves (3 each)
  {
    const int mt0 = wave * 3;
    f32x4 acc[3];
    #pragma unroll
    for (int t = 0; t < 3; ++t) acc[t] = fzero();
    for (int ks = 0; ks < 16; ++ks) {
      const int c0 = ks * 32 + quad * 8;
      bf16x8 bv = ld8(&rout[l15 * 520 + c0]);
      #pragma unroll
      for (int t = 0; t < 3; ++t) {
        bf16x8 av = ld8(&pwb[((mt0 + t) * 16 + l15) * DHC + c0]);
        acc[t] = __builtin_amdgcn_mfma_f32_16x16x32_bf16(av, bv, acc[t], 0, 0, 0);
      }
    }
    float* outb = out + (size_t)b * (OUTC * 16);
    #pragma unroll
    for (int t = 0; t < 3; ++t)
      #pragma unroll
      for (int r = 0; r < 4; ++r) {
        const int oc = (mt0 + t) * 16 + quad * 4 + r;
        const float2 so = bnt[BN_P + oc];
        outb[oc * 16 + l15] = acc[t][r] * so.x + so.y;
      }
  }
}

extern "C" void kernel_launch(void* const* d_in, const int* in_sizes, int n_in,
                              void* d_out, int out_size, void* d_ws, size_t ws_size,
                              hipStream_t stream) {
  const float* x    = (const float*)d_in[0];
  const float* qlw  = (const float*)d_in[1];
  const float* qlb  = (const float*)d_in[2];
  const float* qpw  = (const float*)d_in[3];
  const float* qpb  = (const float*)d_in[4];
  const float* qbn  = (const float*)d_in[5];
  const float* kw   = (const float*)d_in[6];
  const float* kb   = (const float*)d_in[7];
  const float* kbn  = (const float*)d_in[8];
  const float* vw   = (const float*)d_in[9];
  const float* vb   = (const float*)d_in[10];
  const float* vbn  = (const float*)d_in[11];
  const float* vlw  = (const float*)d_in[12];
  const float* vlb  = (const float*)d_in[13];
  const float* vlbn = (const float*)d_in[14];
  const float* pw   = (const float*)d_in[15];
  const float* pb   = (const float*)d_in[16];
  const float* pbn  = (const float*)d_in[17];
  const float* ab   = (const float*)d_in[18];
  const int*   bidx = (const int*)d_in[19];
  const int n_off = in_sizes[18] / 8;
  const int Bn = in_sizes[0] / (DIMC * NPOS);   // 2048

  __hip_bfloat16* wsb = (__hip_bfloat16*)d_ws;  // 983 KB weights + 13 KB BN + 25 KB abf

  prep_weights<<<480, 256, 0, stream>>>(kw, vw, qpw, pw,
                                        kb, kbn, qpb, qbn, vb, vbn,
                                        vlb, vlbn, pb, pbn, ab, bidx, n_off, wsb);
  attn4d_kernel<<<Bn, 512, 0, stream>>>(x, qlw, qlb, vlw, wsb, (float*)d_out);
}

// Round 9
// 879.621 us; speedup vs baseline: 1.0011x; 1.0011x over previous
//
#include <hip/hip_runtime.h>
#include <hip/hip_bf16.h>

// Attention4DDownsample — fused, one workgroup per batch element.
// R11 = R10 body (slim phases, zero scratch: WRITE 53MB, FETCH 95MB) + 
// __launch_bounds__(512, 2).
// Six-round decode of the allocator: hipcc's 2nd launch_bounds arg behaves as
// CUDA min-BLOCKS-per-CU. (…,4) => 32 waves/CU target => 64-reg budget => the
// R5-R9 spill storms. Bare (512) => 128 regs but alloc rounding blocked the 2nd
// workgroup => 1 block/CU resident (Occ 24%). Per-block latency is ~constant
// (~90-100us, weight-load latency + barriers), so throughput ~ resident blocks:
// (512,2) pins budget at exactly 512/4=128 total => 2 blocks/CU co-resident.
// (Resubmitted unchanged: two consecutive GPU-acquisition timeouts, no data.)

#define DIMC 384
#define NPOS 49
#define NHKD 128
#define DHC  512
#define OUTC 384

// ws bf16 weight offsets (elements)
#define OFF_KW  0
#define OFF_VW  49152
#define OFF_QPW 245760
#define OFF_PW  294912
#define W_TOT   491520
// BN fold table (float2, after W_TOT bf16 elems): k,q,v,vl,p
#define BN_K  0
#define BN_Q  128
#define BN_V  256
#define BN_VL 768
#define BN_P  1280
#define BN_TOT 1664
// abf table (f32, after BN table): [8][16*49] gathered bias
#define ABF_ELEMS (8 * 784)

// LDS (bf16 element offsets), total 38,152 elems = 76,304 B (2 blocks/CU)
#define XS_OFF   0        // xs [49][392]; rout [16][520] overlays after vGEMM pass 3
#define KT_OFF   19208    // kt [64][136]; vsm [128][72] (9216) overlays after PD
#define QSM_OFF  27912    // qsm [8][16][16] (2048); tail of vsm's 10752 window
#define QIN_OFF  29960    // qin [16][392]; attnS [8][16][64] (swz) overlays after qGEMM
#define SMEM_ELEMS 38152

typedef __attribute__((ext_vector_type(8))) __bf16 bf16x8;
typedef __attribute__((ext_vector_type(4))) float f32x4;

static __device__ __forceinline__ __hip_bfloat16 f2b(float x) { return __float2bfloat16(x); }
static __device__ __forceinline__ float b2f(__hip_bfloat16 x) { return __bfloat162float(x); }
static __device__ __forceinline__ bf16x8 ld8(const __hip_bfloat16* p) { return *(const bf16x8*)p; }
static __device__ __forceinline__ f32x4 fzero() {
  f32x4 z; z[0] = 0.f; z[1] = 0.f; z[2] = 0.f; z[3] = 0.f; return z;
}
static __device__ __forceinline__ bf16x8 bzero() {
  bf16x8 z;
  #pragma unroll
  for (int j = 0; j < 8; ++j) z[j] = (__bf16)0.0f;
  return z;
}

// ---------------- prep: weights->bf16, BN fold->float2, bias gather->abf ----------------
__global__ void prep_weights(const float* __restrict__ kw, const float* __restrict__ vw,
                             const float* __restrict__ qpw, const float* __restrict__ pw,
                             const float* __restrict__ kb,  const float* __restrict__ kbn,
                             const float* __restrict__ qpb, const float* __restrict__ qbn,
                             const float* __restrict__ vb,  const float* __restrict__ vbn,
                             const float* __restrict__ vlb, const float* __restrict__ vlbn,
                             const float* __restrict__ pb,  const float* __restrict__ pbn,
                             const float* __restrict__ ab,  const int* __restrict__ bidx,
                             int n_off,
                             __hip_bfloat16* __restrict__ wsb) {
  const int gid = blockIdx.x * blockDim.x + threadIdx.x;
  const int stride = gridDim.x * blockDim.x;
  for (int i = gid; i < W_TOT; i += stride) {
    float v;
    if (i < OFF_VW)       v = kw[i - OFF_KW];
    else if (i < OFF_QPW) v = vw[i - OFF_VW];
    else if (i < OFF_PW)  v = qpw[i - OFF_QPW];
    else                  v = pw[i - OFF_PW];
    wsb[i] = f2b(v);
  }
  float2* bnt = (float2*)(wsb + W_TOT);
  for (int i = gid; i < BN_TOT; i += stride) {
    const float *bn, *cb; int ch, C;
    if (i < BN_Q)        { bn = kbn;  cb = kb;  ch = i;         C = NHKD; }
    else if (i < BN_V)   { bn = qbn;  cb = qpb; ch = i - BN_Q;  C = NHKD; }
    else if (i < BN_VL)  { bn = vbn;  cb = vb;  ch = i - BN_V;  C = DHC;  }
    else if (i < BN_P)   { bn = vlbn; cb = vlb; ch = i - BN_VL; C = DHC;  }
    else                 { bn = pbn;  cb = pb;  ch = i - BN_P;  C = OUTC; }
    const float g = bn[ch], be = bn[C + ch], mu = bn[2*C + ch], va = bn[3*C + ch];
    const float s = g * rsqrtf(va + 1e-5f);
    bnt[i] = make_float2(s, be + (cb[ch] - mu) * s);
  }
  float* abf = (float*)((char*)bnt + BN_TOT * 8);
  for (int i = gid; i < ABF_ELEMS; i += stride) {
    const int h = i / 784, j = i - h * 784;
    abf[i] = ab[h * n_off + bidx[j]];
  }
}

// ---------------- main fused kernel ----------------
__global__ __launch_bounds__(512, 2) void attn4d_kernel(
    const float* __restrict__ x,
    const float* __restrict__ qlw, const float* __restrict__ qlb,
    const float* __restrict__ vlw,
    const __hip_bfloat16* __restrict__ wsb,
    float* __restrict__ out)
{
  __shared__ __align__(16) __hip_bfloat16 smem[SMEM_ELEMS];
  __hip_bfloat16* xs    = smem + XS_OFF;     // [49][392]
  __hip_bfloat16* rout  = smem + XS_OFF;     // [16][520], overlays xs post pass-3 vGEMM
  __hip_bfloat16* kt    = smem + KT_OFF;     // [64][136]
  __hip_bfloat16* vsm   = smem + KT_OFF;     // [128][72], overlays kt(+qsm) post-PD
  __hip_bfloat16* qsm   = smem + QSM_OFF;    // [8][16][16]
  __hip_bfloat16* qin   = smem + QIN_OFF;    // [16][392]
  __hip_bfloat16* attnS = smem + QIN_OFF;    // [8][16][64] swz, overlays qin

  const __hip_bfloat16* kwb  = wsb + OFF_KW;
  const __hip_bfloat16* vwb  = wsb + OFF_VW;
  const __hip_bfloat16* qpwb = wsb + OFF_QPW;
  const __hip_bfloat16* pwb  = wsb + OFF_PW;
  const float2* bnt = (const float2*)(wsb + W_TOT);
  const float*  abf = (const float*)((const char*)bnt + BN_TOT * 8);

  const int tid  = threadIdx.x;
  const int lane = tid & 63;
  const int wave = tid >> 6;     // 0..7
  const int quad = lane >> 4;    // 0..3
  const int l15  = lane & 15;
  const int b    = blockIdx.x;

  // ---- P0: stage x[b] (fp32 global) -> xs[n][c] bf16 transposed, b128 LDS writes
  {
    const float* xg = x + (size_t)b * (DIMC * NPOS);
    for (int j = tid; j < NPOS * (DIMC / 8); j += 512) {   // 2352 jobs
      const int n  = j % 49;
      const int c0 = (j / 49) * 8;
      bf16x8 v;
      #pragma unroll
      for (int k = 0; k < 8; ++k)
        v[k] = (__bf16)(xg[(c0 + k) * 49 + n]);
      *(bf16x8*)&xs[n * 392 + c0] = v;
    }
  }
  __syncthreads();   // bar1

  // ---- PA: qin[nq][c] = dw3x3 s2 p1 + avgpool2. Rolling 3x7 window (~35 live).
  if (tid < 384) {
    const int c = tid;
    float wq[9];
    #pragma unroll
    for (int j = 0; j < 9; ++j) wq[j] = qlw[c * 9 + j];
    const float cb = qlb[c];
    #pragma unroll
    for (int oh = 0; oh < 4; ++oh) {
      float w[3][7];   // rows 2oh-1, 2oh, 2oh+1 (zeros when out of range)
      #pragma unroll
      for (int i = 0; i < 7; ++i) {
        w[0][i] = (oh > 0) ? b2f(xs[((2*oh - 1) * 7 + i) * 392 + c]) : 0.f;
        w[1][i] = b2f(xs[((2*oh) * 7 + i) * 392 + c]);
        w[2][i] = (oh < 3) ? b2f(xs[((2*oh + 1) * 7 + i) * 392 + c]) : 0.f;
      }
      #pragma unroll
      for (int ow = 0; ow < 4; ++ow) {
        float a = cb;
        #pragma unroll
        for (int kh = 0; kh < 3; ++kh) {
          #pragma unroll
          for (int kwi = 0; kwi < 3; ++kwi) {
            const int iw = 2 * ow - 1 + kwi;
            if (iw < 0 || iw > 6) continue;
            a += wq[kh * 3 + kwi] * w[kh][iw];
          }
        }
        if (oh < 3 && ow < 3)
          a += 0.25f * (w[1][2*ow] + w[1][2*ow + 1] + w[2][2*ow] + w[2][2*ow + 1]);
        qin[(oh * 4 + ow) * 392 + c] = f2b(a);
      }
    }
  }
  __syncthreads();   // bar2

  // ---- kGEMM: wave = M-tile, 4 N-tiles, per-nt guarded z (live ~25)
  {
    const int mt = wave;
    f32x4 acc[4];
    #pragma unroll
    for (int nt = 0; nt < 4; ++nt) acc[nt] = fzero();
    for (int ks = 0; ks < 12; ++ks) {
      const int c0 = ks * 32 + quad * 8;
      bf16x8 a = ld8(&kwb[(mt * 16 + l15) * DIMC + c0]);
      #pragma unroll
      for (int nt = 0; nt < 4; ++nt) {
        const int n = nt * 16 + l15;
        bf16x8 z = (n < 49) ? ld8(&xs[n * 392 + c0]) : bzero();
        acc[nt] = __builtin_amdgcn_mfma_f32_16x16x32_bf16(a, z, acc[nt], 0, 0, 0);
      }
    }
    #pragma unroll
    for (int r = 0; r < 4; ++r) {
      const int oc = mt * 16 + quad * 4 + r;
      const float2 so = bnt[BN_K + oc];
      #pragma unroll
      for (int nt = 0; nt < 4; ++nt) {
        const int n = nt * 16 + l15;
        if (n < 49) kt[n * 136 + oc] = f2b(acc[nt][r] * so.x + so.y);
        // rows 49..63 stale garbage: feed only masked nk>=49 logits (discarded)
      }
    }
  }

  // ---- qGEMM: wave = M-tile (head) -> qsm[h][nq][kd]
  {
    const int mt = wave;
    f32x4 acc = fzero();
    for (int ks = 0; ks < 12; ++ks) {
      const int c0 = ks * 32 + quad * 8;
      bf16x8 bv = ld8(&qin[l15 * 392 + c0]);
      bf16x8 av = ld8(&qpwb[(mt * 16 + l15) * DIMC + c0]);
      acc = __builtin_amdgcn_mfma_f32_16x16x32_bf16(av, bv, acc, 0, 0, 0);
    }
    #pragma unroll
    for (int r = 0; r < 4; ++r) {
      const int oc = mt * 16 + quad * 4 + r;
      const float2 so = bnt[BN_Q + oc];
      qsm[mt * 256 + l15 * 16 + (oc & 15)] = f2b(acc[r] * so.x + so.y);
    }
  }
  __syncthreads();   // bar3 — kt/qsm ready; qin dead

  // ---- PD: QK^T*scale + abf bias, softmax -> attnS (XOR-swizzled, over dead qin)
  {
    const int h = wave;
    bf16x8 av = (quad < 2) ? ld8(&qsm[h * 256 + l15 * 16 + quad * 8]) : bzero();
    float p[4][4];
    #pragma unroll
    for (int t = 0; t < 4; ++t) {
      bf16x8 bv = (quad < 2) ? ld8(&kt[(t * 16 + l15) * 136 + h * 16 + quad * 8]) : bzero();
      f32x4 lg = __builtin_amdgcn_mfma_f32_16x16x32_bf16(av, bv, fzero(), 0, 0, 0);
      #pragma unroll
      for (int r = 0; r < 4; ++r) {
        const int nq = quad * 4 + r;
        const int nk = t * 16 + l15;
        float val = -30000.f;
        if (nk < 49) val = lg[r] * 0.25f + abf[h * 784 + nq * 49 + nk];
        p[t][r] = val;
      }
    }
    #pragma unroll
    for (int r = 0; r < 4; ++r) {
      float m = fmaxf(fmaxf(p[0][r], p[1][r]), fmaxf(p[2][r], p[3][r]));
      m = fmaxf(m, __shfl_xor(m, 1));
      m = fmaxf(m, __shfl_xor(m, 2));
      m = fmaxf(m, __shfl_xor(m, 4));
      m = fmaxf(m, __shfl_xor(m, 8));
      float e[4], sum = 0.f;
      #pragma unroll
      for (int t = 0; t < 4; ++t) { e[t] = __expf(p[t][r] - m); sum += e[t]; }
      sum += __shfl_xor(sum, 1);
      sum += __shfl_xor(sum, 2);
      sum += __shfl_xor(sum, 4);
      sum += __shfl_xor(sum, 8);
      const float inv = 1.f / sum;
      #pragma unroll
      for (int t = 0; t < 4; ++t) p[t][r] = e[t] * inv;   // exactly 0 for nk>=49
    }
    #pragma unroll
    for (int r = 0; r < 4; ++r) {
      const int nq = quad * 4 + r;
      #pragma unroll
      for (int t = 0; t < 4; ++t) {
        const int nk = t * 16 + l15;
        attnS[h * 1024 + nq * 64 + (nk ^ ((nq & 7) << 3))] = f2b(p[t][r]);
      }
    }
  }
  __syncthreads();   // bar4 — attnS ready; kt/qsm dead (vsm may overlay)

  // ================= v-path: 4 passes x 128 ch, slim accumulators =================
  float res[4][4];   // per-lane relu(xa+vloc) for ch = p*128 + wave*16 + quad*4 + r
  #pragma unroll
  for (int p = 0; p < 4; ++p) {
    // -- vGEMM pass p: wave = (nt = w&3, mgrp = w>>2 -> 4 M-tiles); acc[4] only
    {
      const int nt   = wave & 3;
      const int mgrp = wave >> 2;
      const int n    = nt * 16 + l15;
      f32x4 acc[4];
      #pragma unroll
      for (int i = 0; i < 4; ++i) acc[i] = fzero();
      for (int ks = 0; ks < 12; ++ks) {
        const int c0 = ks * 32 + quad * 8;
        bf16x8 z = (n < 49) ? ld8(&xs[n * 392 + c0]) : bzero();
        #pragma unroll
        for (int i = 0; i < 4; ++i) {
          bf16x8 a = ld8(&vwb[(p * 128 + (mgrp * 4 + i) * 16 + l15) * DIMC + c0]);
          acc[i] = __builtin_amdgcn_mfma_f32_16x16x32_bf16(a, z, acc[i], 0, 0, 0);
        }
      }
      #pragma unroll
      for (int i = 0; i < 4; ++i)
        #pragma unroll
        for (int r = 0; r < 4; ++r) {
          const int chl = (mgrp * 4 + i) * 16 + quad * 4 + r;
          const float2 so = bnt[BN_V + p * 128 + chl];
          // all n incl. 49..63 pads (finite) — PV multiplies pads by attn==0
          vsm[chl * 72 + n] = f2b(acc[i][r] * so.x + so.y);
        }
    }
    __syncthreads();   // barA — vsm pass p ready; (p==3): xs dead

    // -- fused v_local + PV: wave owns 16 ch; lane: ch = quad*4+r, pos = l15
    {
      const int pos = l15, oh = pos >> 2, ow = pos & 3;
      float vloc[4];
      #pragma unroll
      for (int r = 0; r < 4; ++r) {
        const int chl = wave * 16 + quad * 4 + r;
        const int gch = p * 128 + chl;
        float a = 0.f;
        #pragma unroll
        for (int kh = 0; kh < 3; ++kh) {
          #pragma unroll
          for (int kwi = 0; kwi < 3; ++kwi) {
            const int ih = 2 * oh - 1 + kh;
            const int iw = 2 * ow - 1 + kwi;
            const bool ok = ((unsigned)ih <= 6u) && ((unsigned)iw <= 6u);
            const int e = ok ? (ih * 7 + iw) : 0;
            const float tap = b2f(vsm[chl * 72 + e]);
            a += ok ? vlw[gch * 9 + kh * 3 + kwi] * tap : 0.f;
          }
        }
        const float2 so = bnt[BN_VL + gch];
        vloc[r] = a * so.x + so.y;
      }
      const int h = p * 2 + (wave >> 2);
      f32x4 pacc = fzero();
      #pragma unroll
      for (int ks = 0; ks < 2; ++ks) {
        const int k0 = ks * 32 + quad * 8;
        bf16x8 avv = ld8(&vsm[(wave * 16 + l15) * 72 + k0]);                      // A[ch][nk]
        bf16x8 bvv = ld8(&attnS[h * 1024 + l15 * 64 + (k0 ^ ((l15 & 7) << 3))]);  // B[nq][nk]
        pacc = __builtin_amdgcn_mfma_f32_16x16x32_bf16(avv, bvv, pacc, 0, 0, 0);
      }
      #pragma unroll
      for (int r = 0; r < 4; ++r)
        res[p][r] = fmaxf(pacc[r] + vloc[r], 0.f);
    }

    // after pass 3's barA, xs is dead -> flush res to rout (overlays xs)
    if (p == 3) {
      #pragma unroll
      for (int pp = 0; pp < 4; ++pp)
        #pragma unroll
        for (int r = 0; r < 4; ++r) {
          const int gch = pp * 128 + wave * 16 + quad * 4 + r;
          rout[l15 * 520 + gch] = f2b(res[pp][r]);
        }
    }
    __syncthreads();   // barB — vsm reusable / (p==3) rout ready
  }

  // ---- PF: proj GEMM — 24 M-tiles over 8 waves (3 each)
  {
    const int mt0 = wave * 3;
    f32x4 acc[3];
    #pragma unroll
    for (int t = 0; t < 3; ++t) acc[t] = fzero();
    for (int ks = 0; ks < 16; ++ks) {
      const int c0 = ks * 32 + quad * 8;
      bf16x8 bv = ld8(&rout[l15 * 520 + c0]);
      #pragma unroll
      for (int t = 0; t < 3; ++t) {
        bf16x8 av = ld8(&pwb[((mt0 + t) * 16 + l15) * DHC + c0]);
        acc[t] = __builtin_amdgcn_mfma_f32_16x16x32_bf16(av, bv, acc[t], 0, 0, 0);
      }
    }
    float* outb = out + (size_t)b * (OUTC * 16);
    #pragma unroll
    for (int t = 0; t < 3; ++t)
      #pragma unroll
      for (int r = 0; r < 4; ++r) {
        const int oc = (mt0 + t) * 16 + quad * 4 + r;
        const float2 so = bnt[BN_P + oc];
        outb[oc * 16 + l15] = acc[t][r] * so.x + so.y;
      }
  }
}

extern "C" void kernel_launch(void* const* d_in, const int* in_sizes, int n_in,
                              void* d_out, int out_size, void* d_ws, size_t ws_size,
                              hipStream_t stream) {
  const float* x    = (const float*)d_in[0];
  const float* qlw  = (const float*)d_in[1];
  const float* qlb  = (const float*)d_in[2];
  const float* qpw  = (const float*)d_in[3];
  const float* qpb  = (const float*)d_in[4];
  const float* qbn  = (const float*)d_in[5];
  const float* kw   = (const float*)d_in[6];
  const float* kb   = (const float*)d_in[7];
  const float* kbn  = (const float*)d_in[8];
  const float* vw   = (const float*)d_in[9];
  const float* vb   = (const float*)d_in[10];
  const float* vbn  = (const float*)d_in[11];
  const float* vlw  = (const float*)d_in[12];
  const float* vlb  = (const float*)d_in[13];
  const float* vlbn = (const float*)d_in[14];
  const float* pw   = (const float*)d_in[15];
  const float* pb   = (const float*)d_in[16];
  const float* pbn  = (const float*)d_in[17];
  const float* ab   = (const float*)d_in[18];
  const int*   bidx = (const int*)d_in[19];
  const int n_off = in_sizes[18] / 8;
  const int Bn = in_sizes[0] / (DIMC * NPOS);   // 2048

  __hip_bfloat16* wsb = (__hip_bfloat16*)d_ws;  // 983 KB weights + 13 KB BN + 25 KB abf

  prep_weights<<<480, 256, 0, stream>>>(kw, vw, qpw, pw,
                                        kb, kbn, qpb, qbn, vb, vbn,
                                        vlb, vlbn, pb, pbn, ab, bidx, n_off, wsb);
  attn4d_kernel<<<Bn, 512, 0, stream>>>(x, qlw, qlb, vlw, wsb, (float*)d_out);
}